// Round 10
// baseline (29.824 us; speedup 1.0000x reference)
//
#include <hip/hip_runtime.h>
#include <hip/hip_fp16.h>

// LBP forward: out[n,f,h,w] = sum_p 2^p * sigmoid((nb - ctr)/0.1)
//   c  = projection_map[f,p]; ky,kx = kernels[f,p,:] in {0,1,2}
//   nb  = xpad[n,c,h+ky-1,w+kx-1]  (zero pad of 1), ctr = x[n,c,h,w]
// N=32 D=64 H=56 W=56 F=128 P=4
//
// Round-10: compute phase is LDS-PORT-BOUND (r9: removing all transcendentals
// changed nothing; modeled LDS occupancy ~15us matches). Halve LDS traffic:
// tile stored as fp16 VERTICAL PAIRS pre-scaled by -10*log2(e):
//   tile32[(ch*5 + rp)*64 + col] = half2{ S*x[ch, 2rp, col], S*x[ch, 2rp+1, col] }
// Per p: ctr = 2x ds_read2_b32 (rows 0..7), nb = 2x ds_read2_b32 at column
// w+kx-1 (horizontal shift = addressing); vertical shift ky-1=+-1 handled
// in-register with v_alignbit re-pairing under a WAVE-UNIFORM branch (f is
// wave-uniform -> scalar branch). Packed v_pk_sub_f16 gives z = S*(nb-ctr)
// directly (Sterbenz: exact where sigma is sensitive); unpack to f32,
// sigma = rcp(1+exp2(z)) as in r8 (absmax 0.0625 + fp16 quant ~0.1 << 0.3).
// LDS insts/p: 8 -> 4; tile 147KB -> 80KB; stage ds_writes halve.
// Grid 8x32 = 256 blocks = 1/CU; wave-uniform f tables via s_load, one-ahead
// prefetch; lane = column (stride-1, conflict-free).

#define NN 32
#define DD 64
#define HH 56
#define WW 56
#define FF 128
#define PP 4

#define ROWS 7           // output rows per block
#define NRP  5           // row-pairs per channel (tile rows 0..9, row 9 = pad)
#define TCC  64          // padded cols (interior 4..59, zero pads at 3 and 60)
#define COL0 4
#define CHDW (NRP * TCC)       // 320 dwords per channel
#define TILE_DW (DD * CHDW)    // 20480 dwords = 81920 B
#define NTHREADS 1024
#define NWAVES 16
#define FITER (FF / NWAVES)    // 8 f per wave
#define NITEMS (DD * NRP * 14) // 4480 staging items (2 rows x float4 each)
#define SCALE -14.4269504089f  // -10*log2(e)

__device__ __forceinline__ uint32_t ph_sub(uint32_t a, uint32_t b) {
    __half2 ha = *(__half2*)&a, hb = *(__half2*)&b;
    __half2 r  = __hsub2(ha, hb);
    return *(uint32_t*)&r;
}
__device__ __forceinline__ uint32_t alignb(uint32_t hi, uint32_t lo) {
    return (uint32_t)((((uint64_t)hi << 32) | lo) >> 16);  // v_alignbit_b32
}
__device__ __forceinline__ float2 cvt2(uint32_t d) {
    __half2 h = *(__half2*)&d;
    return __half22float2(h);    // .x = lo half (even row), .y = hi half
}

__global__ __launch_bounds__(NTHREADS, 4) void lbp_kernel(
    const float* __restrict__ x,    // (N,D,H,W)
    const int*   __restrict__ kern, // (F,P,2)
    const int*   __restrict__ proj, // (F,P)
    float*       __restrict__ out)  // (N,F,H,W)
{
    __shared__ uint32_t tile32[TILE_DW];   // 80 KB

    const int tid = threadIdx.x;
    const int n   = blockIdx.y;
    const int h0  = blockIdx.x * ROWS;     // 0,7,...,49

    const float* xn = x + (size_t)n * (DD * HH * WW);

    // ---- stage: 4480 items; each = 2 row-float4 loads -> 4 packed dwords ----
    float4 av[5], bv[5];
    int    dst[5];
#pragma unroll
    for (int it = 0; it < 5; ++it) {
        const int item = tid + it * NTHREADS;
        av[it] = make_float4(0.f, 0.f, 0.f, 0.f);
        bv[it] = make_float4(0.f, 0.f, 0.f, 0.f);
        dst[it] = -1;
        if (item < NITEMS) {
            const int ch  = item / (NRP * 14);
            const int rem = item - ch * (NRP * 14);
            const int rp  = rem / 14;
            const int vg  = rem - rp * 14;
            dst[it] = (ch * NRP + rp) * TCC + COL0 + 4 * vg;
            const int h0r = h0 + 2 * rp - 1;          // image row of tile row 2rp
            const float* gp = xn + ch * (HH * WW) + 4 * vg;
            if ((unsigned)h0r < (unsigned)HH)
                av[it] = *(const float4*)(gp + h0r * WW);
            if ((unsigned)(h0r + 1) < (unsigned)HH)
                bv[it] = *(const float4*)(gp + (h0r + 1) * WW);
        }
    }

    // ---- zero pad columns (3 and 60) for every (ch, rp) while loads fly ----
    if (tid < DD * NRP * 2) {
        const int side = tid & 1;
        const int cr   = tid >> 1;                    // ch*NRP + rp
        tile32[cr * TCC + 3 + side * 57] = 0u;
    }

    // ---- pack (scale + fp16 vertical pair) and write b128 ----
#pragma unroll
    for (int it = 0; it < 5; ++it) {
        if (dst[it] >= 0) {
            uint32_t q[4];
            const float4 a = av[it], b = bv[it];
            __half2 h0p = __floats2half2_rn(SCALE * a.x, SCALE * b.x);
            __half2 h1p = __floats2half2_rn(SCALE * a.y, SCALE * b.y);
            __half2 h2p = __floats2half2_rn(SCALE * a.z, SCALE * b.z);
            __half2 h3p = __floats2half2_rn(SCALE * a.w, SCALE * b.w);
            q[0] = *(uint32_t*)&h0p; q[1] = *(uint32_t*)&h1p;
            q[2] = *(uint32_t*)&h2p; q[3] = *(uint32_t*)&h3p;
            *(uint4*)&tile32[dst[it]] = make_uint4(q[0], q[1], q[2], q[3]);
        }
    }
    __syncthreads();

    // ---- compute: wave = f-group, lane = column, 7 rows per lane ----
    const int wid  = __builtin_amdgcn_readfirstlane(tid >> 6);  // 0..15
    const int lane = tid & 63;
    const int w    = lane < WW ? lane : WW - 1;   // clamp idle lanes
    const bool act = lane < WW;
    const int wcol = COL0 + w;

    int f = wid;
    int4 pj = *(const int4*)(proj + f * PP);
    int4 ka = *(const int4*)(kern + f * (PP * 2));
    int4 kb = *(const int4*)(kern + f * (PP * 2) + 4);

#define ACC1(vz, ar) do {                                         \
    const float e_ = __builtin_amdgcn_exp2f(vz);                  \
    ar = fmaf(wt, __builtin_amdgcn_rcpf(1.f + e_), ar);           \
} while (0)

#pragma unroll
    for (int k = 0; k < FITER; ++k) {
        const int fn = f + NWAVES;
        int4 pjn, kan, kbn;
        if (fn < FF) {                  // one-ahead table prefetch (s_load)
            pjn = *(const int4*)(proj + fn * PP);
            kan = *(const int4*)(kern + fn * (PP * 2));
            kbn = *(const int4*)(kern + fn * (PP * 2) + 4);
        }
        const int cc[4]  = {pj.x, pj.y, pj.z, pj.w};
        const int kyv[4] = {ka.x, ka.z, kb.x, kb.z};
        const int kxv[4] = {ka.y, ka.w, kb.y, kb.w};

        float acc[ROWS];
#pragma unroll
        for (int r = 0; r < ROWS; ++r) acc[r] = 0.f;

        float wt = 1.f;
#pragma unroll
        for (int p = 0; p < PP; ++p) {
            const int ky   = kyv[p];                     // SGPR, wave-uniform
            const int base = cc[p] * CHDW + wcol;        // ctr rp0 dword index
            const int na   = base + (kxv[p] - 1) + ((ky == 2) ? TCC : 0);

            const uint32_t c0 = tile32[base];
            const uint32_t c1 = tile32[base + 64];
            const uint32_t c2 = tile32[base + 128];
            const uint32_t c3 = tile32[base + 192];
            const uint32_t n0 = tile32[na];
            const uint32_t n1 = tile32[na + 64];
            const uint32_t n2 = tile32[na + 128];
            const uint32_t n3 = tile32[na + 192];

            uint32_t d0, d1, d2, d3;
            if (ky == 1) {               // wave-uniform scalar branch
                d0 = ph_sub(n0, c0); d1 = ph_sub(n1, c1);
                d2 = ph_sub(n2, c2); d3 = ph_sub(n3, c3);
            } else {                     // vertical shift: re-pair via alignbit
                const uint32_t s0 = alignb(n0, n0);
                const uint32_t s1 = alignb(n1, n0);
                const uint32_t s2 = alignb(n2, n1);
                const uint32_t s3 = alignb(n3, n2);
                d0 = ph_sub(s0, c0); d1 = ph_sub(s1, c1);
                d2 = ph_sub(s2, c2); d3 = ph_sub(s3, c3);
            }
            const float2 f0 = cvt2(d0), f1 = cvt2(d1);
            const float2 f2 = cvt2(d2), f3 = cvt2(d3);
            // slot s = tile row; ctr rows 1..7 -> acc[0..6]; slot0.lo unused
            ACC1(f0.y, acc[0]);
            ACC1(f1.x, acc[1]); ACC1(f1.y, acc[2]);
            ACC1(f2.x, acc[3]); ACC1(f2.y, acc[4]);
            ACC1(f3.x, acc[5]); ACC1(f3.y, acc[6]);
            wt *= 2.f;
        }
        if (act) {
            float* op = out + ((size_t)n * FF + f) * (HH * WW)
                            + (size_t)h0 * WW + w;
#pragma unroll
            for (int r = 0; r < ROWS; ++r) op[r * WW] = acc[r];
        }
        f = fn; pj = pjn; ka = kan; kb = kbn;
    }
#undef ACC1
}

extern "C" void kernel_launch(void* const* d_in, const int* in_sizes, int n_in,
                              void* d_out, int out_size, void* d_ws, size_t ws_size,
                              hipStream_t stream) {
    const float* x    = (const float*)d_in[0];
    const int*   kern = (const int*)d_in[1];
    const int*   proj = (const int*)d_in[2];
    float*       out  = (float*)d_out;

    dim3 grid(HH / ROWS, NN);   // 8 x 32 = 256 blocks = exactly 1 per CU
    dim3 block(NTHREADS);
    lbp_kernel<<<grid, block, 0, stream>>>(x, kern, proj, out);
}

// Round 11
// 26.631 us; speedup vs baseline: 1.1199x; 1.1199x over previous
//
#include <hip/hip_runtime.h>

// LBP forward: out[n,f,h,w] = sum_p 2^p * sigmoid((nb - ctr)/0.1)
//   c  = projection_map[f,p]; ky,kx = kernels[f,p,:] in {0,1,2}
//   nb  = xpad[n,c,h+ky-1,w+kx-1]  (zero pad of 1), ctr = x[n,c,h,w]
// N=32 D=64 H=56 W=56 F=128 P=4
//
// Round-11: compute phase is STALL-bound (r9 trans-free null, r10 LDS-halving
// null/regressed -> per-eval exec cost ~equal in all; observed 21us vs ~9us
// exec floor = waitcnt stalls at 4 waves/SIMD). Fixes:
//  (a) bulk-read-then-math per f-iter: all 56 dwords (4p x 7rows x {ctr,nb})
//      into static-indexed regs first (~32 clustered ds_read2(st64)_b32),
//      ONE lgkmcnt join per f-iter instead of four; join hides under other
//      waves' math.
//  (b) 7-VALU/eval sigmoid, zero trans: 3 fma (abs input-modifier free),
//      v_min3 + v_min, v_bfi copysign, fma accumulate. No tile prescale.
//      max |sigma err| ~0.0095 -> out err <= ~0.19 << 0.3 (r9-verified).
// Grid 8x32 = 256 blocks = exactly 1/CU; 147KB LDS; wave-uniform f with
// s_load tables one-ahead prefetched; lane = column (stride-1, conflict-free).

#define NN 32
#define DD 64
#define HH 56
#define WW 56
#define FF 128
#define PP 4

#define ROWS 7          // output rows per block
#define TR   (ROWS + 2) // 9 tile rows incl. halo
#define TC   64         // padded cols (interior 4..59, zero pads at 3 and 60)
#define COL0 4
#define CHS  (TR * TC)  // 576 floats per channel
#define TILE_FLOATS (DD * CHS)  // 36864 floats = 147456 B
#define NTHREADS 1024
#define NWAVES 16
#define FITER (FF / NWAVES)       // 8 f per wave
#define ITEMS (DD * TR * 14)      // 8064 float4 staging items

__global__ __launch_bounds__(NTHREADS, 4) void lbp_kernel(
    const float* __restrict__ x,    // (N,D,H,W)
    const int*   __restrict__ kern, // (F,P,2)
    const int*   __restrict__ proj, // (F,P)
    float*       __restrict__ out)  // (N,F,H,W)
{
    __shared__ float tile[TILE_FLOATS];  // 147456 B, 1 block/CU

    const int tid = threadIdx.x;
    const int n   = blockIdx.y;
    const int h0  = blockIdx.x * ROWS;   // 0,7,...,49

    const float* xn = x + (size_t)n * (DD * HH * WW);

    // ---- stage: 8064 float4 items, 8/thread; all loads issued up front ----
    float4 rv[8];
    int    lo[8];
#pragma unroll
    for (int it = 0; it < 8; ++it) {
        const int item = tid + it * NTHREADS;
        rv[it] = make_float4(0.f, 0.f, 0.f, 0.f);
        lo[it] = -1;
        if (item < ITEMS) {                       // only it==7 is partial
            const int ch  = item / (TR * 14);
            const int rem = item - ch * (TR * 14);
            const int tr  = rem / 14;
            const int v   = rem - tr * 14;
            lo[it] = ch * CHS + tr * TC + COL0 + 4 * v;
            const int h = h0 + tr - 1;
            if ((unsigned)h < (unsigned)HH)
                rv[it] = *(const float4*)(xn + ch * (HH * WW) + h * WW + 4 * v);
        }
    }

    // ---- zero the kx-pad columns (3 and 60) while loads fly ----
    for (int i = tid; i < DD * TR * 2; i += NTHREADS) {
        const int ch   = i / (TR * 2);
        const int rr   = (i >> 1) % TR;
        const int side = i & 1;
        tile[ch * CHS + rr * TC + 3 + side * 57] = 0.f;
    }

    // ---- land the tile ----
#pragma unroll
    for (int it = 0; it < 8; ++it)
        if (lo[it] >= 0) *(float4*)(tile + lo[it]) = rv[it];
    __syncthreads();

    // ---- compute: wave = f-group, lane = column, 7 rows per lane ----
    const int wid  = __builtin_amdgcn_readfirstlane(tid >> 6);  // 0..15
    const int lane = tid & 63;
    const int w    = lane < WW ? lane : WW - 1;  // clamp idle lanes
    const bool act = lane < WW;
    const int cb   = TC + COL0 + w;              // ctr addr of output row 0

    int f = wid;
    int4 pj = *(const int4*)(proj + f * PP);
    int4 ka = *(const int4*)(kern + f * (PP * 2));
    int4 kb = *(const int4*)(kern + f * (PP * 2) + 4);

#pragma unroll
    for (int k = 0; k < FITER; ++k) {
        const int fn = f + NWAVES;
        int4 pjn, kan, kbn;
        if (fn < FF) {                 // one-ahead table prefetch (s_load)
            pjn = *(const int4*)(proj + fn * PP);
            kan = *(const int4*)(kern + fn * (PP * 2));
            kbn = *(const int4*)(kern + fn * (PP * 2) + 4);
        }
        const int cc[4]  = {pj.x, pj.y, pj.z, pj.w};
        const int kyv[4] = {ka.x, ka.z, kb.x, kb.z};
        const int kxv[4] = {ka.y, ka.w, kb.y, kb.w};

        // ---- (a) bulk reads: all 56 dwords, static indexing, one join ----
        float cv[PP][ROWS], nv[PP][ROWS];
#pragma unroll
        for (int p = 0; p < PP; ++p) {
            const int pc = cc[p] * CHS + cb;                      // ctr row 0
            const int pn = pc + (kyv[p] - 1) * TC + (kxv[p] - 1); // neighbor
#pragma unroll
            for (int r = 0; r < ROWS; ++r) {
                cv[p][r] = tile[pc + r * TC];
                nv[p][r] = tile[pn + r * TC];
            }
        }

        // ---- (b) straight-line trans-free math: 7 VALU per eval ----
        float acc[ROWS];
#pragma unroll
        for (int r = 0; r < ROWS; ++r) acc[r] = 7.5f;  // sum wt * 0.5
#pragma unroll
        for (int p = 0; p < PP; ++p) {
            const float wt = (float)(1 << p);
#pragma unroll
            for (int r = 0; r < ROWS; ++r) {
                const float d  = nv[p][r] - cv[p][r];
                const float ad = __builtin_fabsf(d);              // modifier
                const float u0 = fmaf(2.5f,     ad, -0.0078f);
                const float u1 = fmaf(1.49146f, ad,  0.08455f);
                const float u2 = fmaf(0.45177f, ad,  0.30774f);
                const float um = fminf(fminf(fminf(u0, u1), u2), 0.49140f);
                acc[r] = fmaf(wt, __builtin_copysignf(um, d), acc[r]);
            }
        }

        if (act) {
            float* op = out + ((size_t)n * FF + f) * (HH * WW)
                            + (size_t)h0 * WW + w;
#pragma unroll
            for (int r = 0; r < ROWS; ++r) op[r * WW] = acc[r];
        }
        f = fn; pj = pjn; ka = kan; kb = kbn;
    }
}

extern "C" void kernel_launch(void* const* d_in, const int* in_sizes, int n_in,
                              void* d_out, int out_size, void* d_ws, size_t ws_size,
                              hipStream_t stream) {
    const float* x    = (const float*)d_in[0];
    const int*   kern = (const int*)d_in[1];
    const int*   proj = (const int*)d_in[2];
    float*       out  = (float*)d_out;

    dim3 grid(HH / ROWS, NN);   // 8 x 32 = 256 blocks = exactly 1 per CU
    dim3 block(NTHREADS);
    lbp_kernel<<<grid, block, 0, stream>>>(x, kern, proj, out);
}